// Round 3
// baseline (1289.288 us; speedup 1.0000x reference)
//
#include <hip/hip_runtime.h>

typedef __bf16 bf16x8 __attribute__((ext_vector_type(8)));
typedef float floatx4 __attribute__((ext_vector_type(4)));

static __device__ __forceinline__ float bfu_to_f(unsigned short u) {
    unsigned int x = ((unsigned int)u) << 16;
    return __builtin_bit_cast(float, x);
}
static __device__ __forceinline__ unsigned short f_to_bfu(float f) {
    unsigned int u = __builtin_bit_cast(unsigned int, f);
    unsigned int r = (u + 0x7fffu + ((u >> 16) & 1u)) >> 16;
    return (unsigned short)r;
}

// ---------------- dtype detection ----------------
// flags[0] = 1 if float tensors are bf16, 0 if float32
// flags[1] = 1 if edge_index is int64, 0 if int32
__global__ void detect_k(const unsigned short* __restrict__ bih_u,
                         const unsigned int* __restrict__ ei_u,
                         int* __restrict__ flags) {
    if (threadIdx.x == 0 && blockIdx.x == 0) {
        int votes = 0;
        for (int i = 0; i < 64; i++) {
            // even-indexed uint16: bf16 element (small exponent field) vs f32 low
            // mantissa half (uniform bits)
            unsigned short u = bih_u[2 * i];
            unsigned int ex = (u >> 7) & 0xFF;
            if (ex >= 64 && ex < 124) votes++;
        }
        flags[0] = (votes >= 48) ? 1 : 0;
        int zeros = 0;
        for (int i = 0; i < 64; i++) {
            if (ei_u[2 * i + 1] == 0u) zeros++;  // int64 high words all 0 (vals < 2^31)
        }
        flags[1] = (zeros == 64) ? 1 : 0;
    }
}

// ---------------- canonicalization ----------------

__global__ void cvt_bf16_k(const void* __restrict__ in, unsigned short* __restrict__ out,
                           int n, const int* __restrict__ flags) {
    int i = blockIdx.x * 256 + threadIdx.x;
    if (i >= n) return;
    if (flags[0]) out[i] = ((const unsigned short*)in)[i];
    else out[i] = f_to_bfu(((const float*)in)[i]);
}

__global__ void cvt_f32_k(const void* __restrict__ in, float* __restrict__ out,
                          int n, const int* __restrict__ flags) {
    int i = blockIdx.x * 256 + threadIdx.x;
    if (i >= n) return;
    if (flags[0]) out[i] = bfu_to_f(((const unsigned short*)in)[i]);
    else out[i] = ((const float*)in)[i];
}

// final output: widen bf16 hidden state to f32, or copy raw u16, per detected dtype
__global__ void out_k(const unsigned short* __restrict__ xb, void* __restrict__ out,
                      int n, const int* __restrict__ flags) {
    int i = blockIdx.x * 256 + threadIdx.x;
    if (i >= n) return;
    if (flags[0]) ((unsigned short*)out)[i] = xb[i];
    else ((float*)out)[i] = bfu_to_f(xb[i]);
}

// ---------------- CSR build ----------------

static __device__ __forceinline__ int load_idx(const unsigned int* eiu, size_t pos, int is64) {
    return (int)eiu[is64 ? 2 * pos : pos];
}

__global__ void hist_k(const unsigned int* __restrict__ eiu, int* __restrict__ deg, int E,
                       const int* __restrict__ flags) {
    int e = blockIdx.x * 256 + threadIdx.x;
    if (e < E) {
        int d = load_idx(eiu, (size_t)E + e, flags[1]);
        atomicAdd(&deg[d], 1);
    }
}

#define SCAN_B 1024
__global__ void scan1_k(const int* __restrict__ deg, int* __restrict__ offsets,
                        int* __restrict__ bsums, int N) {
    __shared__ int sh[SCAN_B];
    int t = threadIdx.x;
    int i = blockIdx.x * SCAN_B + t;
    int v = (i < N) ? deg[i] : 0;
    sh[t] = v;
    __syncthreads();
    for (int off = 1; off < SCAN_B; off <<= 1) {
        int u = (t >= off) ? sh[t - off] : 0;
        __syncthreads();
        sh[t] += u;
        __syncthreads();
    }
    if (i < N) offsets[i] = sh[t] - v;  // block-local exclusive
    if (t == SCAN_B - 1) bsums[blockIdx.x] = sh[t];
}

__global__ void scan2_k(int* __restrict__ bsums, int nb) {
    __shared__ int sh[128];
    int t = threadIdx.x;
    int v = (t < nb) ? bsums[t] : 0;
    sh[t] = v;
    __syncthreads();
    for (int off = 1; off < 128; off <<= 1) {
        int u = (t >= off) ? sh[t - off] : 0;
        __syncthreads();
        sh[t] += u;
        __syncthreads();
    }
    if (t < nb) bsums[t] = sh[t] - v;  // exclusive
}

__global__ void scan3_k(int* __restrict__ offsets, const int* __restrict__ bsums,
                        int* __restrict__ cursor, int N, int E) {
    int i = blockIdx.x * SCAN_B + threadIdx.x;
    if (i < N) {
        int o = offsets[i] + bsums[blockIdx.x];
        offsets[i] = o;
        cursor[i] = o;
    }
    if (i == 0) offsets[N] = E;
}

__global__ void scatter_k(const unsigned int* __restrict__ eiu, const void* __restrict__ ew,
                          int* __restrict__ cursor, int* __restrict__ es,
                          float* __restrict__ ews, int E, const int* __restrict__ flags) {
    int e = blockIdx.x * 256 + threadIdx.x;
    if (e < E) {
        int is64 = flags[1];
        int s = load_idx(eiu, (size_t)e, is64);
        int d = load_idx(eiu, (size_t)E + e, is64);
        float w = flags[0] ? bfu_to_f(((const unsigned short*)ew)[e])
                           : ((const float*)ew)[e];
        int p = atomicAdd(&cursor[d], 1);
        es[p] = s;
        ews[p] = w;
    }
}

// ---------------- Ut_l[j][a] = sum_k W_l[a][k] * w_ih[j][k] ----------------

__global__ void make_ut_k(const void* __restrict__ weight, const void* __restrict__ wih,
                          unsigned short* __restrict__ Ut, const int* __restrict__ flags) {
    int idx = blockIdx.x * 256 + threadIdx.x;  // l*49152 + j*128 + a
    if (idx >= 3 * 384 * 128) return;
    int isb = flags[0];
    int a = idx & 127;
    int j = (idx >> 7) % 384;
    int l = idx / (384 * 128);
    const unsigned short* Wb = (const unsigned short*)weight;
    const float* Wf = (const float*)weight;
    const unsigned short* Ib = (const unsigned short*)wih;
    const float* If = (const float*)wih;
    int wbase = l * 16384 + a * 128;  // weight[l][a][:]
    int ibase = j * 128;              // w_ih[j][:]
    float s = 0.f;
    if (isb) {
        for (int k = 0; k < 128; k++) s += bfu_to_f(Wb[wbase + k]) * bfu_to_f(Ib[ibase + k]);
    } else {
        for (int k = 0; k < 128; k++) s += Wf[wbase + k] * If[ibase + k];
    }
    Ut[idx] = f_to_bfu(s);
}

// ---------------- aggregation: y[n,:] = sum_{e: dst=n} w_e * xb[src_e,:] ----------------

__global__ __launch_bounds__(256) void agg_k(const unsigned short* __restrict__ xb,
                                             const int* __restrict__ offs,
                                             const int* __restrict__ es,
                                             const float* __restrict__ ews,
                                             unsigned short* __restrict__ y, int N) {
    int wave = (int)((blockIdx.x * 256 + threadIdx.x) >> 6);
    int lane = threadIdx.x & 63;
    if (wave >= N) return;
    int b = offs[wave];
    int e2 = offs[wave + 1];
    float a0 = 0.f, a1 = 0.f;
    const unsigned int* xp = (const unsigned int*)xb;  // row = 64 uints (128 bf16)
    for (int e = b; e < e2; e++) {
        int s = es[e];
        float w = ews[e];
        unsigned int v = xp[(size_t)s * 64 + lane];
        float f0 = __builtin_bit_cast(float, v << 16);
        float f1 = __builtin_bit_cast(float, v & 0xffff0000u);
        a0 += w * f0;
        a1 += w * f1;
    }
    unsigned int out = ((unsigned int)f_to_bfu(a0)) | (((unsigned int)f_to_bfu(a1)) << 16);
    ((unsigned int*)y)[(size_t)wave * 64 + lane] = out;
}

// ---------------- fused GRU: gi = y@Ut^T, gh = xb@whh^T, gates, write xb ----------------

__global__ __launch_bounds__(256) void gru_k(const unsigned short* __restrict__ y,
                                             unsigned short* __restrict__ xb,
                                             const unsigned short* __restrict__ Ut,
                                             const unsigned short* __restrict__ whh,
                                             const float* __restrict__ bih,
                                             const float* __restrict__ bhh, int N) {
    int tid = threadIdx.x;
    int wave = tid >> 6;
    int lane = tid & 63;
    int quad = lane >> 4;
    int m16 = lane & 15;
    int row0 = blockIdx.x * 16;
    int colBase = wave * 32;

    floatx4 accI[3][2];
    floatx4 accH[3][2];
#pragma unroll
    for (int g = 0; g < 3; g++)
#pragma unroll
        for (int t = 0; t < 2; t++) {
            accI[g][t] = (floatx4){0.f, 0.f, 0.f, 0.f};
            accH[g][t] = (floatx4){0.f, 0.f, 0.f, 0.f};
        }

    int arow = row0 + m16;
    if (arow >= N) arow = N - 1;

#pragma unroll
    for (int kk = 0; kk < 128; kk += 32) {
        bf16x8 aY = *(const bf16x8*)(y + (size_t)arow * 128 + kk + quad * 8);
        bf16x8 aX = *(const bf16x8*)(xb + (size_t)arow * 128 + kk + quad * 8);
#pragma unroll
        for (int g = 0; g < 3; g++) {
#pragma unroll
            for (int t = 0; t < 2; t++) {
                int col0 = g * 128 + colBase + t * 16;
                bf16x8 bU = *(const bf16x8*)(Ut + (size_t)(col0 + m16) * 128 + kk + quad * 8);
                bf16x8 bW = *(const bf16x8*)(whh + (size_t)(col0 + m16) * 128 + kk + quad * 8);
                accI[g][t] = __builtin_amdgcn_mfma_f32_16x16x32_bf16(aY, bU, accI[g][t], 0, 0, 0);
                accH[g][t] = __builtin_amdgcn_mfma_f32_16x16x32_bf16(aX, bW, accH[g][t], 0, 0, 0);
            }
        }
    }

    __syncthreads();  // all waves done reading xb rows before in-place writes

#pragma unroll
    for (int t = 0; t < 2; t++) {
        int ch = colBase + t * 16 + m16;  // 0..127
        float bi_r = bih[ch], bh_r = bhh[ch];
        float bi_z = bih[128 + ch], bh_z = bhh[128 + ch];
        float bi_n = bih[256 + ch], bh_n = bhh[256 + ch];
#pragma unroll
        for (int ri = 0; ri < 4; ri++) {
            int row = row0 + quad * 4 + ri;
            if (row >= N) continue;
            float gir = accI[0][t][ri] + bi_r, ghr = accH[0][t][ri] + bh_r;
            float giz = accI[1][t][ri] + bi_z, ghz = accH[1][t][ri] + bh_z;
            float gin = accI[2][t][ri] + bi_n, ghn = accH[2][t][ri] + bh_n;
            float r = 1.f / (1.f + __expf(-(gir + ghr)));
            float zg = 1.f / (1.f + __expf(-(giz + ghz)));
            float n = tanhf(gin + r * ghn);
            float h = bfu_to_f(xb[(size_t)row * 128 + ch]);
            float o = (1.f - zg) * n + zg * h;
            xb[(size_t)row * 128 + ch] = f_to_bfu(o);
        }
    }
}

// ---------------- launch ----------------

extern "C" void kernel_launch(void* const* d_in, const int* in_sizes, int n_in,
                              void* d_out, int out_size, void* d_ws, size_t ws_size,
                              hipStream_t stream) {
    const int N = in_sizes[0] / 128;
    const int E = in_sizes[1];

    const void* z = d_in[0];
    const void* ew = d_in[1];
    const void* weight = d_in[2];
    const void* wih = d_in[3];
    const void* whh = d_in[4];
    const void* bih = d_in[5];
    const void* bhh = d_in[6];
    const unsigned int* eiu = (const unsigned int*)d_in[7];

    // y (per-layer aggregation, bf16 N*128 = 25.6MB) aliases d_out — it is dead
    // before the final out_k write. d_out is at least N*128*2 bytes in either
    // output dtype.
    unsigned short* y = (unsigned short*)d_out;

    // workspace carve (256B aligned)
    size_t off = 0;
    char* base = (char*)d_ws;
    auto carve = [&](size_t bytes) -> void* {
        void* p = base + off;
        off = (off + bytes + 255) & ~(size_t)255;
        return p;
    };
    unsigned short* xb = (unsigned short*)carve((size_t)N * 128 * 2);  // bf16 hidden state
    int* es = (int*)carve((size_t)E * 4);
    float* ews = (float*)carve((size_t)E * 4);
    int* offsets = (int*)carve((size_t)(N + 1) * 4);
    int* cursor = (int*)carve((size_t)N * 4);
    int* deg = (int*)carve((size_t)N * 4);
    int* bsums = (int*)carve(1024 * 4);
    unsigned short* Ut = (unsigned short*)carve((size_t)3 * 384 * 128 * 2);
    unsigned short* whh_b = (unsigned short*)carve((size_t)384 * 128 * 2);
    float* bih_f = (float*)carve(384 * 4);
    float* bhh_f = (float*)carve(384 * 4);
    int* flags = (int*)carve(256);

    // dtype detection
    detect_k<<<1, 64, 0, stream>>>((const unsigned short*)bih, eiu, flags);

    // canonicalize inputs
    cvt_bf16_k<<<(N * 128 + 255) / 256, 256, 0, stream>>>(z, xb, N * 128, flags);
    cvt_bf16_k<<<(384 * 128 + 255) / 256, 256, 0, stream>>>(whh, whh_b, 384 * 128, flags);
    cvt_f32_k<<<2, 256, 0, stream>>>(bih, bih_f, 384, flags);
    cvt_f32_k<<<2, 256, 0, stream>>>(bhh, bhh_f, 384, flags);

    // CSR build
    hipMemsetAsync(deg, 0, (size_t)N * 4, stream);
    hist_k<<<(E + 255) / 256, 256, 0, stream>>>(eiu, deg, E, flags);
    int nb = (N + SCAN_B - 1) / SCAN_B;
    scan1_k<<<nb, SCAN_B, 0, stream>>>(deg, offsets, bsums, N);
    scan2_k<<<1, 128, 0, stream>>>(bsums, nb);
    scan3_k<<<nb, SCAN_B, 0, stream>>>(offsets, bsums, cursor, N, E);
    scatter_k<<<(E + 255) / 256, 256, 0, stream>>>(eiu, ew, cursor, es, ews, E, flags);

    // fused weights
    make_ut_k<<<(3 * 384 * 128 + 255) / 256, 256, 0, stream>>>(weight, wih, Ut, flags);

    for (int l = 0; l < 3; l++) {
        agg_k<<<(N + 3) / 4, 256, 0, stream>>>(xb, offsets, es, ews, y, N);
        gru_k<<<(N + 15) / 16, 256, 0, stream>>>(y, xb, Ut + (size_t)l * 384 * 128, whh_b,
                                                 bih_f, bhh_f, N);
    }

    // final output in detected dtype
    out_k<<<(N * 128 + 255) / 256, 256, 0, stream>>>(xb, d_out, N * 128, flags);
}

// Round 4
// 798.914 us; speedup vs baseline: 1.6138x; 1.6138x over previous
//
#include <hip/hip_runtime.h>

typedef __bf16 bf16x8 __attribute__((ext_vector_type(8)));
typedef float floatx4 __attribute__((ext_vector_type(4)));

static __device__ __forceinline__ float bfu_to_f(unsigned short u) {
    unsigned int x = ((unsigned int)u) << 16;
    return __builtin_bit_cast(float, x);
}
static __device__ __forceinline__ unsigned short f_to_bfu(float f) {
    unsigned int u = __builtin_bit_cast(unsigned int, f);
    unsigned int r = (u + 0x7fffu + ((u >> 16) & 1u)) >> 16;
    return (unsigned short)r;
}

// ---------------- dtype detection ----------------
// flags[0] = 1 if float tensors are bf16, 0 if float32
// flags[1] = 1 if edge_index is int64, 0 if int32
__global__ void detect_k(const unsigned short* __restrict__ bih_u,
                         const unsigned int* __restrict__ ei_u,
                         int* __restrict__ flags) {
    if (threadIdx.x == 0 && blockIdx.x == 0) {
        int votes = 0;
        for (int i = 0; i < 64; i++) {
            unsigned short u = bih_u[2 * i];
            unsigned int ex = (u >> 7) & 0xFF;
            if (ex >= 64 && ex < 124) votes++;
        }
        flags[0] = (votes >= 48) ? 1 : 0;
        int zeros = 0;
        for (int i = 0; i < 64; i++) {
            if (ei_u[2 * i + 1] == 0u) zeros++;
        }
        flags[1] = (zeros == 64) ? 1 : 0;
    }
}

// ---------------- canonicalization ----------------

__global__ void cvt_bf16_k(const void* __restrict__ in, unsigned short* __restrict__ out,
                           int n, const int* __restrict__ flags) {
    int i = blockIdx.x * 256 + threadIdx.x;
    if (i >= n) return;
    if (flags[0]) out[i] = ((const unsigned short*)in)[i];
    else out[i] = f_to_bfu(((const float*)in)[i]);
}

__global__ void cvt_f32_k(const void* __restrict__ in, float* __restrict__ out,
                          int n, const int* __restrict__ flags) {
    int i = blockIdx.x * 256 + threadIdx.x;
    if (i >= n) return;
    if (flags[0]) out[i] = bfu_to_f(((const unsigned short*)in)[i]);
    else out[i] = ((const float*)in)[i];
}

__global__ void out_k(const unsigned short* __restrict__ xb, void* __restrict__ out,
                      int n, const int* __restrict__ flags) {
    int i = blockIdx.x * 256 + threadIdx.x;
    if (i >= n) return;
    if (flags[0]) ((unsigned short*)out)[i] = xb[i];
    else ((float*)out)[i] = bfu_to_f(xb[i]);
}

// ---------------- CSR build ----------------

static __device__ __forceinline__ int load_idx(const unsigned int* eiu, size_t pos, int is64) {
    return (int)eiu[is64 ? 2 * pos : pos];
}

__global__ void hist_k(const unsigned int* __restrict__ eiu, int* __restrict__ deg, int E,
                       const int* __restrict__ flags) {
    int e = blockIdx.x * 256 + threadIdx.x;
    if (e < E) {
        int d = load_idx(eiu, (size_t)E + e, flags[1]);
        atomicAdd(&deg[d], 1);
    }
}

#define SCAN_B 1024
__global__ void scan1_k(const int* __restrict__ deg, int* __restrict__ offsets,
                        int* __restrict__ bsums, int N) {
    __shared__ int sh[SCAN_B];
    int t = threadIdx.x;
    int i = blockIdx.x * SCAN_B + t;
    int v = (i < N) ? deg[i] : 0;
    sh[t] = v;
    __syncthreads();
    for (int off = 1; off < SCAN_B; off <<= 1) {
        int u = (t >= off) ? sh[t - off] : 0;
        __syncthreads();
        sh[t] += u;
        __syncthreads();
    }
    if (i < N) offsets[i] = sh[t] - v;
    if (t == SCAN_B - 1) bsums[blockIdx.x] = sh[t];
}

__global__ void scan2_k(int* __restrict__ bsums, int nb) {
    __shared__ int sh[128];
    int t = threadIdx.x;
    int v = (t < nb) ? bsums[t] : 0;
    sh[t] = v;
    __syncthreads();
    for (int off = 1; off < 128; off <<= 1) {
        int u = (t >= off) ? sh[t - off] : 0;
        __syncthreads();
        sh[t] += u;
        __syncthreads();
    }
    if (t < nb) bsums[t] = sh[t] - v;
}

__global__ void scan3_k(int* __restrict__ offsets, const int* __restrict__ bsums,
                        int* __restrict__ cursor, int N, int E) {
    int i = blockIdx.x * SCAN_B + threadIdx.x;
    if (i < N) {
        int o = offsets[i] + bsums[blockIdx.x];
        offsets[i] = o;
        cursor[i] = o;
    }
    if (i == 0) offsets[N] = E;
}

__global__ void scatter_k(const unsigned int* __restrict__ eiu, const void* __restrict__ ew,
                          int* __restrict__ cursor, int* __restrict__ es,
                          float* __restrict__ ews, int E, const int* __restrict__ flags) {
    int e = blockIdx.x * 256 + threadIdx.x;
    if (e < E) {
        int is64 = flags[1];
        int s = load_idx(eiu, (size_t)e, is64);
        int d = load_idx(eiu, (size_t)E + e, is64);
        float w = flags[0] ? bfu_to_f(((const unsigned short*)ew)[e])
                           : ((const float*)ew)[e];
        int p = atomicAdd(&cursor[d], 1);
        es[p] = s;
        ews[p] = w;
    }
}

// ---------------- Ut_l[j][a] = sum_k W_l[a][k] * w_ih[j][k] ----------------

__global__ void make_ut_k(const void* __restrict__ weight, const void* __restrict__ wih,
                          unsigned short* __restrict__ Ut, const int* __restrict__ flags) {
    int idx = blockIdx.x * 256 + threadIdx.x;  // l*49152 + j*128 + a
    if (idx >= 3 * 384 * 128) return;
    int isb = flags[0];
    int a = idx & 127;
    int j = (idx >> 7) % 384;
    int l = idx / (384 * 128);
    const unsigned short* Wb = (const unsigned short*)weight;
    const float* Wf = (const float*)weight;
    const unsigned short* Ib = (const unsigned short*)wih;
    const float* If = (const float*)wih;
    int wbase = l * 16384 + a * 128;
    int ibase = j * 128;
    float s = 0.f;
    if (isb) {
        for (int k = 0; k < 128; k++) s += bfu_to_f(Wb[wbase + k]) * bfu_to_f(Ib[ibase + k]);
    } else {
        for (int k = 0; k < 128; k++) s += Wf[wbase + k] * If[ibase + k];
    }
    Ut[idx] = f_to_bfu(s);
}

// ---------------- pack weights into MFMA B-fragment order ----------------
// Bp[l][ct][kc][lane][8]: ct 0..23 = Ut col-tiles (col = (ct%24)*16 + lane&15),
// ct 24..47 = whh col-tiles; kc = K-chunk of 32; lane fragment = 8 bf16 at
// k = kc*32 + (lane>>4)*8. Wave-coalesced 1KB per (ct,kc).
__global__ void pack_b_k(const unsigned short* __restrict__ Ut,
                         const unsigned short* __restrict__ whh_b,
                         unsigned short* __restrict__ Bp) {
    int idx = blockIdx.x * 256 + threadIdx.x;  // 3*48*4*64 total
    if (idx >= 3 * 48 * 4 * 64) return;
    int l = idx / 12288;
    int rem = idx % 12288;
    int ct = rem >> 8;
    int kc = (rem >> 6) & 3;
    int lane = rem & 63;
    int col = (ct % 24) * 16 + (lane & 15);
    int k = kc * 32 + (lane >> 4) * 8;
    const unsigned short* src = (ct < 24) ? (Ut + (size_t)l * 49152 + col * 128 + k)
                                          : (whh_b + (size_t)col * 128 + k);
    unsigned short* dst = Bp + (size_t)l * 98304 + ((size_t)(ct * 4 + kc) * 64 + lane) * 8;
    *(uint4*)dst = *(const uint4*)src;
}

// ---------------- aggregation: y[n,:] = sum_{e: dst=n} w_e * xb[src_e,:] ----------------
// One wave per node; 4 edges in flight (16 lanes x 16B cover a 256B row each).

__global__ __launch_bounds__(256) void agg_k(const unsigned short* __restrict__ xb,
                                             const int* __restrict__ offs,
                                             const int* __restrict__ es,
                                             const float* __restrict__ ews,
                                             unsigned short* __restrict__ y, int N) {
    int node = (int)((blockIdx.x * 256 + threadIdx.x) >> 6);
    int lane = threadIdx.x & 63;
    if (node >= N) return;
    int grp = lane >> 4;
    int l16 = lane & 15;
    int b = offs[node];
    int e2 = offs[node + 1];
    float acc[8];
#pragma unroll
    for (int i = 0; i < 8; i++) acc[i] = 0.f;
    const uint4* xp4 = (const uint4*)xb;  // row = 16 uint4
    for (int e = b + grp; e < e2; e += 4) {
        int s = es[e];
        float w = ews[e];
        uint4 v = xp4[(size_t)s * 16 + l16];
        acc[0] += w * __builtin_bit_cast(float, v.x << 16);
        acc[1] += w * __builtin_bit_cast(float, v.x & 0xffff0000u);
        acc[2] += w * __builtin_bit_cast(float, v.y << 16);
        acc[3] += w * __builtin_bit_cast(float, v.y & 0xffff0000u);
        acc[4] += w * __builtin_bit_cast(float, v.z << 16);
        acc[5] += w * __builtin_bit_cast(float, v.z & 0xffff0000u);
        acc[6] += w * __builtin_bit_cast(float, v.w << 16);
        acc[7] += w * __builtin_bit_cast(float, v.w & 0xffff0000u);
    }
#pragma unroll
    for (int i = 0; i < 8; i++) {
        acc[i] += __shfl_xor(acc[i], 16);
        acc[i] += __shfl_xor(acc[i], 32);
    }
    if (grp == 0) {
        uint4 o;
        o.x = (unsigned int)f_to_bfu(acc[0]) | ((unsigned int)f_to_bfu(acc[1]) << 16);
        o.y = (unsigned int)f_to_bfu(acc[2]) | ((unsigned int)f_to_bfu(acc[3]) << 16);
        o.z = (unsigned int)f_to_bfu(acc[4]) | ((unsigned int)f_to_bfu(acc[5]) << 16);
        o.w = (unsigned int)f_to_bfu(acc[6]) | ((unsigned int)f_to_bfu(acc[7]) << 16);
        ((uint4*)y)[(size_t)node * 16 + l16] = o;
    }
}

// ---------------- fused GRU: gi = y@Ut^T, gh = xin@whh^T, gates, write xout ----------------
// Block = 256 threads / 4 waves, M = 32 rows. Wave w owns channels [w*32, w*32+32).
// B operand from packed Bp (coalesced). xout is a separate buffer: no barrier needed.

__global__ __launch_bounds__(256) void gru_k(const unsigned short* __restrict__ y,
                                             const unsigned short* __restrict__ xin,
                                             unsigned short* __restrict__ xout,
                                             const unsigned short* __restrict__ Bp,
                                             const float* __restrict__ bih,
                                             const float* __restrict__ bhh, int N) {
    int tid = threadIdx.x;
    int wave = tid >> 6;
    int lane = tid & 63;
    int quad = lane >> 4;
    int m16 = lane & 15;
    int row0 = blockIdx.x * 32;

    floatx4 acc[2][2][6];  // [mt][t][g*2+p], p=0 -> gi (Ut), p=1 -> gh (whh)
#pragma unroll
    for (int mt = 0; mt < 2; mt++)
#pragma unroll
        for (int t = 0; t < 2; t++)
#pragma unroll
            for (int m = 0; m < 6; m++) acc[mt][t][m] = (floatx4){0.f, 0.f, 0.f, 0.f};

    int rA0 = row0 + m16;
    int rA1 = row0 + 16 + m16;
    if (rA0 >= N) rA0 = N - 1;
    if (rA1 >= N) rA1 = N - 1;

#pragma unroll
    for (int kc = 0; kc < 4; kc++) {
        int ko = kc * 32 + quad * 8;
        bf16x8 aY0 = *(const bf16x8*)(y + (size_t)rA0 * 128 + ko);
        bf16x8 aY1 = *(const bf16x8*)(y + (size_t)rA1 * 128 + ko);
        bf16x8 aX0 = *(const bf16x8*)(xin + (size_t)rA0 * 128 + ko);
        bf16x8 aX1 = *(const bf16x8*)(xin + (size_t)rA1 * 128 + ko);
#pragma unroll
        for (int t = 0; t < 2; t++) {
            int ctt = wave * 2 + t;
#pragma unroll
            for (int g = 0; g < 3; g++) {
                int ctU = g * 8 + ctt;
                bf16x8 bU = *(const bf16x8*)(Bp + ((size_t)(ctU * 4 + kc) * 64 + lane) * 8);
                acc[0][t][g * 2 + 0] =
                    __builtin_amdgcn_mfma_f32_16x16x32_bf16(aY0, bU, acc[0][t][g * 2 + 0], 0, 0, 0);
                acc[1][t][g * 2 + 0] =
                    __builtin_amdgcn_mfma_f32_16x16x32_bf16(aY1, bU, acc[1][t][g * 2 + 0], 0, 0, 0);
                int ctW = 24 + g * 8 + ctt;
                bf16x8 bW = *(const bf16x8*)(Bp + ((size_t)(ctW * 4 + kc) * 64 + lane) * 8);
                acc[0][t][g * 2 + 1] =
                    __builtin_amdgcn_mfma_f32_16x16x32_bf16(aX0, bW, acc[0][t][g * 2 + 1], 0, 0, 0);
                acc[1][t][g * 2 + 1] =
                    __builtin_amdgcn_mfma_f32_16x16x32_bf16(aX1, bW, acc[1][t][g * 2 + 1], 0, 0, 0);
            }
        }
    }

#pragma unroll
    for (int t = 0; t < 2; t++) {
        int ch = wave * 32 + t * 16 + m16;
        float bi_r = bih[ch], bh_r = bhh[ch];
        float bi_z = bih[128 + ch], bh_z = bhh[128 + ch];
        float bi_n = bih[256 + ch], bh_n = bhh[256 + ch];
#pragma unroll
        for (int mt = 0; mt < 2; mt++) {
#pragma unroll
            for (int ri = 0; ri < 4; ri++) {
                int row = row0 + mt * 16 + quad * 4 + ri;
                if (row >= N) continue;
                float gir = acc[mt][t][0][ri] + bi_r, ghr = acc[mt][t][1][ri] + bh_r;
                float giz = acc[mt][t][2][ri] + bi_z, ghz = acc[mt][t][3][ri] + bh_z;
                float gin = acc[mt][t][4][ri] + bi_n, ghn = acc[mt][t][5][ri] + bh_n;
                float r = 1.f / (1.f + __expf(-(gir + ghr)));
                float zg = 1.f / (1.f + __expf(-(giz + ghz)));
                float n = tanhf(gin + r * ghn);
                float h = bfu_to_f(xin[(size_t)row * 128 + ch]);
                float o = (1.f - zg) * n + zg * h;
                xout[(size_t)row * 128 + ch] = f_to_bfu(o);
            }
        }
    }
}

// ---------------- launch ----------------

extern "C" void kernel_launch(void* const* d_in, const int* in_sizes, int n_in,
                              void* d_out, int out_size, void* d_ws, size_t ws_size,
                              hipStream_t stream) {
    const int N = in_sizes[0] / 128;
    const int E = in_sizes[1];

    const void* z = d_in[0];
    const void* ew = d_in[1];
    const void* weight = d_in[2];
    const void* wih = d_in[3];
    const void* whh = d_in[4];
    const void* bih = d_in[5];
    const void* bhh = d_in[6];
    const unsigned int* eiu = (const unsigned int*)d_in[7];

    // y (bf16 N*128 = 25.6MB) aliases d_out — dead before final out_k write.
    unsigned short* y = (unsigned short*)d_out;

    size_t off = 0;
    char* base = (char*)d_ws;
    auto carve = [&](size_t bytes) -> void* {
        void* p = base + off;
        off = (off + bytes + 255) & ~(size_t)255;
        return p;
    };
    unsigned short* xb = (unsigned short*)carve((size_t)N * 128 * 2);
    unsigned short* xb2 = (unsigned short*)carve((size_t)N * 128 * 2);
    int* es = (int*)carve((size_t)E * 4);
    float* ews = (float*)carve((size_t)E * 4);
    int* offsets = (int*)carve((size_t)(N + 1) * 4);
    int* cursor = (int*)carve((size_t)N * 4);
    int* deg = (int*)carve((size_t)N * 4);
    int* bsums = (int*)carve(1024 * 4);
    unsigned short* Ut = (unsigned short*)carve((size_t)3 * 384 * 128 * 2);
    unsigned short* whh_b = (unsigned short*)carve((size_t)384 * 128 * 2);
    unsigned short* Bp = (unsigned short*)carve((size_t)3 * 48 * 4 * 64 * 8 * 2);
    float* bih_f = (float*)carve(384 * 4);
    float* bhh_f = (float*)carve(384 * 4);
    int* flags = (int*)carve(256);

    detect_k<<<1, 64, 0, stream>>>((const unsigned short*)bih, eiu, flags);

    cvt_bf16_k<<<(N * 128 + 255) / 256, 256, 0, stream>>>(z, xb, N * 128, flags);
    cvt_bf16_k<<<(384 * 128 + 255) / 256, 256, 0, stream>>>(whh, whh_b, 384 * 128, flags);
    cvt_f32_k<<<2, 256, 0, stream>>>(bih, bih_f, 384, flags);
    cvt_f32_k<<<2, 256, 0, stream>>>(bhh, bhh_f, 384, flags);

    hipMemsetAsync(deg, 0, (size_t)N * 4, stream);
    hist_k<<<(E + 255) / 256, 256, 0, stream>>>(eiu, deg, E, flags);
    int nb = (N + SCAN_B - 1) / SCAN_B;
    scan1_k<<<nb, SCAN_B, 0, stream>>>(deg, offsets, bsums, N);
    scan2_k<<<1, 128, 0, stream>>>(bsums, nb);
    scan3_k<<<nb, SCAN_B, 0, stream>>>(offsets, bsums, cursor, N, E);
    scatter_k<<<(E + 255) / 256, 256, 0, stream>>>(eiu, ew, cursor, es, ews, E, flags);

    make_ut_k<<<(3 * 384 * 128 + 255) / 256, 256, 0, stream>>>(weight, wih, Ut, flags);
    pack_b_k<<<(3 * 48 * 4 * 64 + 255) / 256, 256, 0, stream>>>(Ut, whh_b, Bp);

    const unsigned short* cur = xb;
    unsigned short* nxt = xb2;
    for (int l = 0; l < 3; l++) {
        agg_k<<<(N + 3) / 4, 256, 0, stream>>>(cur, offsets, es, ews, y, N);
        gru_k<<<(N + 31) / 32, 256, 0, stream>>>(y, cur, nxt, Bp + (size_t)l * 98304,
                                                 bih_f, bhh_f, N);
        const unsigned short* tmp = cur;
        cur = nxt;
        nxt = (unsigned short*)tmp;
    }

    out_k<<<(N * 128 + 255) / 256, 256, 0, stream>>>(cur, d_out, N * 128, flags);
}

// Round 5
// 795.526 us; speedup vs baseline: 1.6207x; 1.0043x over previous
//
#include <hip/hip_runtime.h>

typedef __bf16 bf16x8 __attribute__((ext_vector_type(8)));
typedef float floatx4 __attribute__((ext_vector_type(4)));

static __device__ __forceinline__ float bfu_to_f(unsigned short u) {
    unsigned int x = ((unsigned int)u) << 16;
    return __builtin_bit_cast(float, x);
}
static __device__ __forceinline__ unsigned short f_to_bfu(float f) {
    unsigned int u = __builtin_bit_cast(unsigned int, f);
    unsigned int r = (u + 0x7fffu + ((u >> 16) & 1u)) >> 16;
    return (unsigned short)r;
}

// ---------------- dtype detection ----------------
// flags[0] = 1 if float tensors are bf16, 0 if float32
// flags[1] = 1 if edge_index is int64, 0 if int32
__global__ void detect_k(const unsigned short* __restrict__ bih_u,
                         const unsigned int* __restrict__ ei_u,
                         int* __restrict__ flags) {
    if (threadIdx.x == 0 && blockIdx.x == 0) {
        int votes = 0;
        for (int i = 0; i < 64; i++) {
            unsigned short u = bih_u[2 * i];
            unsigned int ex = (u >> 7) & 0xFF;
            if (ex >= 64 && ex < 124) votes++;
        }
        flags[0] = (votes >= 48) ? 1 : 0;
        int zeros = 0;
        for (int i = 0; i < 64; i++) {
            if (ei_u[2 * i + 1] == 0u) zeros++;
        }
        flags[1] = (zeros == 64) ? 1 : 0;
    }
}

// ---------------- canonicalization ----------------

__global__ void cvt_bf16_k(const void* __restrict__ in, unsigned short* __restrict__ out,
                           int n, const int* __restrict__ flags) {
    int i = blockIdx.x * 256 + threadIdx.x;
    if (i >= n) return;
    if (flags[0]) out[i] = ((const unsigned short*)in)[i];
    else out[i] = f_to_bfu(((const float*)in)[i]);
}

__global__ void cvt_bias_k(const void* __restrict__ bih, const void* __restrict__ bhh,
                           float* __restrict__ bih_f, float* __restrict__ bhh_f,
                           const int* __restrict__ flags) {
    int i = blockIdx.x * 256 + threadIdx.x;
    if (i >= 768) return;
    const void* src = (i < 384) ? bih : bhh;
    int j = (i < 384) ? i : i - 384;
    float v = flags[0] ? bfu_to_f(((const unsigned short*)src)[j]) : ((const float*)src)[j];
    if (i < 384) bih_f[j] = v;
    else bhh_f[j] = v;
}

__global__ void out_k(const unsigned short* __restrict__ xb, void* __restrict__ out,
                      int n, const int* __restrict__ flags) {
    int i = blockIdx.x * 256 + threadIdx.x;
    if (i >= n) return;
    if (flags[0]) ((unsigned short*)out)[i] = xb[i];
    else ((float*)out)[i] = bfu_to_f(xb[i]);
}

// ---------------- CSR build ----------------

static __device__ __forceinline__ int load_idx(const unsigned int* eiu, size_t pos, int is64) {
    return (int)eiu[is64 ? 2 * pos : pos];
}

__global__ void hist_k(const unsigned int* __restrict__ eiu, int* __restrict__ deg, int E,
                       const int* __restrict__ flags) {
    int e = blockIdx.x * 256 + threadIdx.x;
    if (e < E) {
        int d = load_idx(eiu, (size_t)E + e, flags[1]);
        atomicAdd(&deg[d], 1);
    }
}

#define SCAN_B 1024
__global__ void scan1_k(const int* __restrict__ deg, int* __restrict__ offsets,
                        int* __restrict__ bsums, int N) {
    __shared__ int sh[SCAN_B];
    int t = threadIdx.x;
    int i = blockIdx.x * SCAN_B + t;
    int v = (i < N) ? deg[i] : 0;
    sh[t] = v;
    __syncthreads();
    for (int off = 1; off < SCAN_B; off <<= 1) {
        int u = (t >= off) ? sh[t - off] : 0;
        __syncthreads();
        sh[t] += u;
        __syncthreads();
    }
    if (i < N) offsets[i] = sh[t] - v;
    if (t == SCAN_B - 1) bsums[blockIdx.x] = sh[t];
}

__global__ void scan2_k(int* __restrict__ bsums, int nb) {
    __shared__ int sh[128];
    int t = threadIdx.x;
    int v = (t < nb) ? bsums[t] : 0;
    sh[t] = v;
    __syncthreads();
    for (int off = 1; off < 128; off <<= 1) {
        int u = (t >= off) ? sh[t - off] : 0;
        __syncthreads();
        sh[t] += u;
        __syncthreads();
    }
    if (t < nb) bsums[t] = sh[t] - v;
}

__global__ void scan3_k(int* __restrict__ offsets, const int* __restrict__ bsums,
                        int* __restrict__ cursor, int N, int E) {
    int i = blockIdx.x * SCAN_B + threadIdx.x;
    if (i < N) {
        int o = offsets[i] + bsums[blockIdx.x];
        offsets[i] = o;
        cursor[i] = o;
    }
    if (i == 0) offsets[N] = E;
}

// one 8B record per edge: .x = src node, .y = bit-cast f32 edge weight
__global__ void scatter_k(const unsigned int* __restrict__ eiu, const void* __restrict__ ew,
                          int* __restrict__ cursor, uint2* __restrict__ rec,
                          int E, const int* __restrict__ flags) {
    int e = blockIdx.x * 256 + threadIdx.x;
    if (e < E) {
        int is64 = flags[1];
        int s = load_idx(eiu, (size_t)e, is64);
        int d = load_idx(eiu, (size_t)E + e, is64);
        float w = flags[0] ? bfu_to_f(((const unsigned short*)ew)[e])
                           : ((const float*)ew)[e];
        int p = atomicAdd(&cursor[d], 1);
        rec[p] = make_uint2((unsigned int)s, __builtin_bit_cast(unsigned int, w));
    }
}

// ---------------- Ut_l[j][a] = sum_k W_l[a][k] * w_ih[j][k] ----------------

__global__ void make_ut_k(const void* __restrict__ weight, const void* __restrict__ wih,
                          unsigned short* __restrict__ Ut, const int* __restrict__ flags) {
    int idx = blockIdx.x * 256 + threadIdx.x;  // l*49152 + j*128 + a
    if (idx >= 3 * 384 * 128) return;
    int isb = flags[0];
    int a = idx & 127;
    int j = (idx >> 7) % 384;
    int l = idx / (384 * 128);
    const unsigned short* Wb = (const unsigned short*)weight;
    const float* Wf = (const float*)weight;
    const unsigned short* Ib = (const unsigned short*)wih;
    const float* If = (const float*)wih;
    int wbase = l * 16384 + a * 128;
    int ibase = j * 128;
    float s = 0.f;
    if (isb) {
        for (int k = 0; k < 128; k++) s += bfu_to_f(Wb[wbase + k]) * bfu_to_f(Ib[ibase + k]);
    } else {
        for (int k = 0; k < 128; k++) s += Wf[wbase + k] * If[ibase + k];
    }
    Ut[idx] = f_to_bfu(s);
}

// ---------------- pack weights into MFMA B-fragment order ----------------
// Bp[l][ct][kc][lane][8]: ct 0..23 = Ut col-tiles (col = (ct%24)*16 + lane&15),
// ct 24..47 = whh col-tiles; kc = K-chunk of 32; lane fragment = 8 bf16 at
// k = kc*32 + (lane>>4)*8. whh is read dtype-aware (conversion folded in).
__global__ void pack_b_k(const unsigned short* __restrict__ Ut,
                         const void* __restrict__ whh,
                         unsigned short* __restrict__ Bp,
                         const int* __restrict__ flags) {
    int idx = blockIdx.x * 256 + threadIdx.x;  // 3*48*4*64 total
    if (idx >= 3 * 48 * 4 * 64) return;
    int l = idx / 12288;
    int rem = idx % 12288;
    int ct = rem >> 8;
    int kc = (rem >> 6) & 3;
    int lane = rem & 63;
    int col = (ct % 24) * 16 + (lane & 15);
    int k = kc * 32 + (lane >> 4) * 8;
    unsigned short tmp[8];
    const unsigned short* src;
    if (ct < 24) {
        src = Ut + (size_t)l * 49152 + col * 128 + k;
    } else if (flags[0]) {
        src = (const unsigned short*)whh + (size_t)col * 128 + k;
    } else {
        const float* wf = (const float*)whh + (size_t)col * 128 + k;
        for (int i = 0; i < 8; i++) tmp[i] = f_to_bfu(wf[i]);
        src = tmp;
    }
    unsigned short* dst = Bp + (size_t)l * 98304 + ((size_t)(ct * 4 + kc) * 64 + lane) * 8;
    for (int i = 0; i < 8; i++) dst[i] = src[i];
}

// ---------------- aggregation: y[n,:] = sum_{e: dst=n} w_e * xb[src_e,:] ----------------
// One node per 16-lane group (4 nodes/wave); 4-edge unroll -> 16 row-gathers in
// flight per wave. Two accumulator chains for FMA ILP.

__global__ __launch_bounds__(256) void agg_k(const unsigned short* __restrict__ xb,
                                             const int* __restrict__ offs,
                                             const uint2* __restrict__ rec,
                                             unsigned short* __restrict__ y, int N) {
    int node = (int)((blockIdx.x * 256 + threadIdx.x) >> 4);
    int l16 = threadIdx.x & 15;
    if (node >= N) return;
    int b = offs[node];
    int e2 = offs[node + 1];
    const uint4* xp4 = (const uint4*)xb;  // row = 16 uint4
    float a0[8], a1[8];
#pragma unroll
    for (int i = 0; i < 8; i++) { a0[i] = 0.f; a1[i] = 0.f; }

    auto fma_row = [&](float* acc, uint4 v, float w) {
        acc[0] += w * __builtin_bit_cast(float, v.x << 16);
        acc[1] += w * __builtin_bit_cast(float, v.x & 0xffff0000u);
        acc[2] += w * __builtin_bit_cast(float, v.y << 16);
        acc[3] += w * __builtin_bit_cast(float, v.y & 0xffff0000u);
        acc[4] += w * __builtin_bit_cast(float, v.z << 16);
        acc[5] += w * __builtin_bit_cast(float, v.z & 0xffff0000u);
        acc[6] += w * __builtin_bit_cast(float, v.w << 16);
        acc[7] += w * __builtin_bit_cast(float, v.w & 0xffff0000u);
    };

    int e = b;
    for (; e + 4 <= e2; e += 4) {
        uint2 r0 = rec[e], r1 = rec[e + 1], r2 = rec[e + 2], r3 = rec[e + 3];
        uint4 v0 = xp4[(size_t)r0.x * 16 + l16];
        uint4 v1 = xp4[(size_t)r1.x * 16 + l16];
        uint4 v2 = xp4[(size_t)r2.x * 16 + l16];
        uint4 v3 = xp4[(size_t)r3.x * 16 + l16];
        fma_row(a0, v0, __builtin_bit_cast(float, r0.y));
        fma_row(a1, v1, __builtin_bit_cast(float, r1.y));
        fma_row(a0, v2, __builtin_bit_cast(float, r2.y));
        fma_row(a1, v3, __builtin_bit_cast(float, r3.y));
    }
    for (; e < e2; e++) {
        uint2 r = rec[e];
        uint4 v = xp4[(size_t)r.x * 16 + l16];
        fma_row(a0, v, __builtin_bit_cast(float, r.y));
    }

    uint4 o;
    o.x = (unsigned int)f_to_bfu(a0[0] + a1[0]) | ((unsigned int)f_to_bfu(a0[1] + a1[1]) << 16);
    o.y = (unsigned int)f_to_bfu(a0[2] + a1[2]) | ((unsigned int)f_to_bfu(a0[3] + a1[3]) << 16);
    o.z = (unsigned int)f_to_bfu(a0[4] + a1[4]) | ((unsigned int)f_to_bfu(a0[5] + a1[5]) << 16);
    o.w = (unsigned int)f_to_bfu(a0[6] + a1[6]) | ((unsigned int)f_to_bfu(a0[7] + a1[7]) << 16);
    ((uint4*)y)[(size_t)node * 16 + l16] = o;
}

// ---------------- fused GRU: gi = y@Ut^T, gh = xin@whh^T, gates, write xout ----------------
// Block = 256 threads / 4 waves, M = 32 rows. Wave w owns channels [w*32, w*32+32).

__global__ __launch_bounds__(256) void gru_k(const unsigned short* __restrict__ y,
                                             const unsigned short* __restrict__ xin,
                                             unsigned short* __restrict__ xout,
                                             const unsigned short* __restrict__ Bp,
                                             const float* __restrict__ bih,
                                             const float* __restrict__ bhh, int N) {
    int tid = threadIdx.x;
    int wave = tid >> 6;
    int lane = tid & 63;
    int quad = lane >> 4;
    int m16 = lane & 15;
    int row0 = blockIdx.x * 32;

    floatx4 acc[2][2][6];  // [mt][t][g*2+p], p=0 -> gi (Ut), p=1 -> gh (whh)
#pragma unroll
    for (int mt = 0; mt < 2; mt++)
#pragma unroll
        for (int t = 0; t < 2; t++)
#pragma unroll
            for (int m = 0; m < 6; m++) acc[mt][t][m] = (floatx4){0.f, 0.f, 0.f, 0.f};

    int rA0 = row0 + m16;
    int rA1 = row0 + 16 + m16;
    if (rA0 >= N) rA0 = N - 1;
    if (rA1 >= N) rA1 = N - 1;

#pragma unroll
    for (int kc = 0; kc < 4; kc++) {
        int ko = kc * 32 + quad * 8;
        bf16x8 aY0 = *(const bf16x8*)(y + (size_t)rA0 * 128 + ko);
        bf16x8 aY1 = *(const bf16x8*)(y + (size_t)rA1 * 128 + ko);
        bf16x8 aX0 = *(const bf16x8*)(xin + (size_t)rA0 * 128 + ko);
        bf16x8 aX1 = *(const bf16x8*)(xin + (size_t)rA1 * 128 + ko);
#pragma unroll
        for (int t = 0; t < 2; t++) {
            int ctt = wave * 2 + t;
#pragma unroll
            for (int g = 0; g < 3; g++) {
                int ctU = g * 8 + ctt;
                bf16x8 bU = *(const bf16x8*)(Bp + ((size_t)(ctU * 4 + kc) * 64 + lane) * 8);
                acc[0][t][g * 2 + 0] =
                    __builtin_amdgcn_mfma_f32_16x16x32_bf16(aY0, bU, acc[0][t][g * 2 + 0], 0, 0, 0);
                acc[1][t][g * 2 + 0] =
                    __builtin_amdgcn_mfma_f32_16x16x32_bf16(aY1, bU, acc[1][t][g * 2 + 0], 0, 0, 0);
                int ctW = 24 + g * 8 + ctt;
                bf16x8 bW = *(const bf16x8*)(Bp + ((size_t)(ctW * 4 + kc) * 64 + lane) * 8);
                acc[0][t][g * 2 + 1] =
                    __builtin_amdgcn_mfma_f32_16x16x32_bf16(aX0, bW, acc[0][t][g * 2 + 1], 0, 0, 0);
                acc[1][t][g * 2 + 1] =
                    __builtin_amdgcn_mfma_f32_16x16x32_bf16(aX1, bW, acc[1][t][g * 2 + 1], 0, 0, 0);
            }
        }
    }

#pragma unroll
    for (int t = 0; t < 2; t++) {
        int ch = wave * 32 + t * 16 + m16;
        float bi_r = bih[ch], bh_r = bhh[ch];
        float bi_z = bih[128 + ch], bh_z = bhh[128 + ch];
        float bi_n = bih[256 + ch], bh_n = bhh[256 + ch];
#pragma unroll
        for (int mt = 0; mt < 2; mt++) {
#pragma unroll
            for (int ri = 0; ri < 4; ri++) {
                int row = row0 + mt * 16 + quad * 4 + ri;
                if (row >= N) continue;
                float gir = acc[mt][t][0][ri] + bi_r, ghr = acc[mt][t][1][ri] + bh_r;
                float giz = acc[mt][t][2][ri] + bi_z, ghz = acc[mt][t][3][ri] + bh_z;
                float gin = acc[mt][t][4][ri] + bi_n, ghn = acc[mt][t][5][ri] + bh_n;
                float r = 1.f / (1.f + __expf(-(gir + ghr)));
                float zg = 1.f / (1.f + __expf(-(giz + ghz)));
                float n = tanhf(gin + r * ghn);
                float h = bfu_to_f(xin[(size_t)row * 128 + ch]);
                float o = (1.f - zg) * n + zg * h;
                xout[(size_t)row * 128 + ch] = f_to_bfu(o);
            }
        }
    }
}

// ---------------- launch ----------------

extern "C" void kernel_launch(void* const* d_in, const int* in_sizes, int n_in,
                              void* d_out, int out_size, void* d_ws, size_t ws_size,
                              hipStream_t stream) {
    const int N = in_sizes[0] / 128;
    const int E = in_sizes[1];

    const void* z = d_in[0];
    const void* ew = d_in[1];
    const void* weight = d_in[2];
    const void* wih = d_in[3];
    const void* whh = d_in[4];
    const void* bih = d_in[5];
    const void* bhh = d_in[6];
    const unsigned int* eiu = (const unsigned int*)d_in[7];

    // y (bf16 N*128 = 25.6MB) aliases d_out — dead before final out_k write.
    unsigned short* y = (unsigned short*)d_out;

    size_t off = 0;
    char* base = (char*)d_ws;
    auto carve = [&](size_t bytes) -> void* {
        void* p = base + off;
        off = (off + bytes + 255) & ~(size_t)255;
        return p;
    };
    unsigned short* xb = (unsigned short*)carve((size_t)N * 128 * 2);
    unsigned short* xb2 = (unsigned short*)carve((size_t)N * 128 * 2);
    uint2* rec = (uint2*)carve((size_t)E * 8);
    int* offsets = (int*)carve((size_t)(N + 1) * 4);
    int* cursor = (int*)carve((size_t)N * 4);
    int* deg = (int*)carve((size_t)N * 4);
    int* bsums = (int*)carve(1024 * 4);
    unsigned short* Ut = (unsigned short*)carve((size_t)3 * 384 * 128 * 2);
    unsigned short* Bp = (unsigned short*)carve((size_t)3 * 48 * 4 * 64 * 8 * 2);
    float* bih_f = (float*)carve(384 * 4);
    float* bhh_f = (float*)carve(384 * 4);
    int* flags = (int*)carve(256);

    detect_k<<<1, 64, 0, stream>>>((const unsigned short*)bih, eiu, flags);

    cvt_bf16_k<<<(N * 128 + 255) / 256, 256, 0, stream>>>(z, xb, N * 128, flags);
    cvt_bias_k<<<3, 256, 0, stream>>>(bih, bhh, bih_f, bhh_f, flags);

    hipMemsetAsync(deg, 0, (size_t)N * 4, stream);
    hist_k<<<(E + 255) / 256, 256, 0, stream>>>(eiu, deg, E, flags);
    int nb = (N + SCAN_B - 1) / SCAN_B;
    scan1_k<<<nb, SCAN_B, 0, stream>>>(deg, offsets, bsums, N);
    scan2_k<<<1, 128, 0, stream>>>(bsums, nb);
    scan3_k<<<nb, SCAN_B, 0, stream>>>(offsets, bsums, cursor, N, E);
    scatter_k<<<(E + 255) / 256, 256, 0, stream>>>(eiu, ew, cursor, rec, E, flags);

    make_ut_k<<<(3 * 384 * 128 + 255) / 256, 256, 0, stream>>>(weight, wih, Ut, flags);
    pack_b_k<<<(3 * 48 * 4 * 64 + 255) / 256, 256, 0, stream>>>(Ut, whh, Bp, flags);

    const unsigned short* cur = xb;
    unsigned short* nxt = xb2;
    for (int l = 0; l < 3; l++) {
        agg_k<<<(N + 15) / 16, 256, 0, stream>>>(cur, offsets, rec, y, N);
        gru_k<<<(N + 31) / 32, 256, 0, stream>>>(y, cur, nxt, Bp + (size_t)l * 98304,
                                                 bih_f, bhh_f, N);
        const unsigned short* tmp = cur;
        cur = nxt;
        nxt = (unsigned short*)tmp;
    }

    out_k<<<(N * 128 + 255) / 256, 256, 0, stream>>>(cur, d_out, N * 128, flags);
}

// Round 6
// 744.404 us; speedup vs baseline: 1.7320x; 1.0687x over previous
//
#include <hip/hip_runtime.h>

typedef __bf16 bf16x8 __attribute__((ext_vector_type(8)));
typedef float floatx4 __attribute__((ext_vector_type(4)));

#define NPB 256        // nodes per bucket (power of 2)
#define NPB_SHIFT 8
#define MAXNB 1024     // max buckets supported (N <= 262144)
#define TILE 16384     // edges per binning block

static __device__ __forceinline__ float bfu_to_f(unsigned short u) {
    unsigned int x = ((unsigned int)u) << 16;
    return __builtin_bit_cast(float, x);
}
static __device__ __forceinline__ unsigned short f_to_bfu(float f) {
    unsigned int u = __builtin_bit_cast(unsigned int, f);
    unsigned int r = (u + 0x7fffu + ((u >> 16) & 1u)) >> 16;
    return (unsigned short)r;
}

// ---------------- dtype detection ----------------
// flags[0] = 1 if float tensors are bf16, 0 if float32
// flags[1] = 1 if edge_index is int64, 0 if int32
__global__ void detect_k(const unsigned short* __restrict__ bih_u,
                         const unsigned int* __restrict__ ei_u,
                         int* __restrict__ flags) {
    if (threadIdx.x == 0 && blockIdx.x == 0) {
        int votes = 0;
        for (int i = 0; i < 64; i++) {
            unsigned short u = bih_u[2 * i];
            unsigned int ex = (u >> 7) & 0xFF;
            if (ex >= 64 && ex < 124) votes++;
        }
        flags[0] = (votes >= 48) ? 1 : 0;
        int zeros = 0;
        for (int i = 0; i < 64; i++) {
            if (ei_u[2 * i + 1] == 0u) zeros++;
        }
        flags[1] = (zeros == 64) ? 1 : 0;
    }
}

// ---------------- canonicalization ----------------

__global__ void cvt_bf16_k(const void* __restrict__ in, unsigned short* __restrict__ out,
                           int n, const int* __restrict__ flags) {
    int i = blockIdx.x * 256 + threadIdx.x;
    if (i >= n) return;
    if (flags[0]) out[i] = ((const unsigned short*)in)[i];
    else out[i] = f_to_bfu(((const float*)in)[i]);
}

__global__ void cvt_bias_k(const void* __restrict__ bih, const void* __restrict__ bhh,
                           float* __restrict__ bih_f, float* __restrict__ bhh_f,
                           const int* __restrict__ flags) {
    int i = blockIdx.x * 256 + threadIdx.x;
    if (i >= 768) return;
    const void* src = (i < 384) ? bih : bhh;
    int j = (i < 384) ? i : i - 384;
    float v = flags[0] ? bfu_to_f(((const unsigned short*)src)[j]) : ((const float*)src)[j];
    if (i < 384) bih_f[j] = v;
    else bhh_f[j] = v;
}

__global__ void out_k(const unsigned short* __restrict__ xb, void* __restrict__ out,
                      int n, const int* __restrict__ flags) {
    int i = blockIdx.x * 256 + threadIdx.x;
    if (i >= n) return;
    if (flags[0]) ((unsigned short*)out)[i] = xb[i];
    else ((float*)out)[i] = bfu_to_f(xb[i]);
}

// ---------------- hierarchical CSR build ----------------

static __device__ __forceinline__ int load_idx(const unsigned int* eiu, size_t pos, int is64) {
    return (int)eiu[is64 ? 2 * pos : pos];
}

// A1: per-block LDS histogram over buckets -> global bucket counts (~NB atomics/block)
__global__ __launch_bounds__(256) void count_k(const unsigned int* __restrict__ eiu,
                                               int* __restrict__ bucketCnt, int E,
                                               const int* __restrict__ flags) {
    __shared__ int cnt[MAXNB];
    int t = threadIdx.x;
    for (int b = t; b < MAXNB; b += 256) cnt[b] = 0;
    __syncthreads();
    int is64 = flags[1];
    int e0 = blockIdx.x * TILE;
    int e1 = min(e0 + TILE, E);
    for (int e = e0 + t; e < e1; e += 256) {
        int d = load_idx(eiu, (size_t)E + e, is64);
        atomicAdd(&cnt[d >> NPB_SHIFT], 1);
    }
    __syncthreads();
    for (int b = t; b < MAXNB; b += 256) {
        int c = cnt[b];
        if (c) atomicAdd(&bucketCnt[b], c);
    }
}

// scan over bucket counts -> bucketBase (exclusive), bucketCursor copy
__global__ void scanB_k(const int* __restrict__ bucketCnt, int* __restrict__ bucketBase,
                        int* __restrict__ bucketCursor, int NB, int E) {
    __shared__ int sh[MAXNB];
    int t = threadIdx.x;  // 1024 threads
    int v = (t < NB) ? bucketCnt[t] : 0;
    sh[t] = v;
    __syncthreads();
    for (int off = 1; off < MAXNB; off <<= 1) {
        int u = (t >= off) ? sh[t - off] : 0;
        __syncthreads();
        sh[t] += u;
        __syncthreads();
    }
    if (t < NB) {
        int b = sh[t] - v;
        bucketBase[t] = b;
        bucketCursor[t] = b;
    }
    if (t == 0) bucketBase[NB] = E;
}

// A2: bin edges into bucket-contiguous regions (per-block chunk reservation + LDS cursors)
__global__ __launch_bounds__(256) void bin_k(const unsigned int* __restrict__ eiu,
                                             const void* __restrict__ ew,
                                             int* __restrict__ bucketCursor,
                                             uint2* __restrict__ rec8,
                                             int* __restrict__ dstA, int E,
                                             const int* __restrict__ flags) {
    __shared__ int cnt[MAXNB];
    __shared__ int basel[MAXNB];
    int t = threadIdx.x;
    for (int b = t; b < MAXNB; b += 256) cnt[b] = 0;
    __syncthreads();
    int is64 = flags[1];
    int isb = flags[0];
    int e0 = blockIdx.x * TILE;
    int e1 = min(e0 + TILE, E);
    for (int e = e0 + t; e < e1; e += 256) {
        int d = load_idx(eiu, (size_t)E + e, is64);
        atomicAdd(&cnt[d >> NPB_SHIFT], 1);
    }
    __syncthreads();
    for (int b = t; b < MAXNB; b += 256) {
        int c = cnt[b];
        basel[b] = c ? atomicAdd(&bucketCursor[b], c) : 0;
        cnt[b] = 0;
    }
    __syncthreads();
    for (int e = e0 + t; e < e1; e += 256) {
        int s = load_idx(eiu, (size_t)e, is64);
        int d = load_idx(eiu, (size_t)E + e, is64);
        float w = isb ? bfu_to_f(((const unsigned short*)ew)[e]) : ((const float*)ew)[e];
        int b = d >> NPB_SHIFT;
        int p = basel[b] + atomicAdd(&cnt[b], 1);
        dstA[p] = d;
        rec8[p] = make_uint2((unsigned int)s, __builtin_bit_cast(unsigned int, w));
    }
}

// B: per-bucket node histogram + scan + CSR placement + offsets write (no global atomics)
__global__ __launch_bounds__(256) void csr_k(const uint2* __restrict__ rec8,
                                             const int* __restrict__ dstA,
                                             const int* __restrict__ bucketBase,
                                             int* __restrict__ offsets,
                                             uint2* __restrict__ rec, int N, int E) {
    __shared__ int cnt[NPB];
    __shared__ int sh[NPB];
    __shared__ int cur[NPB];
    int t = threadIdx.x;
    int b = blockIdx.x;
    int n0 = b << NPB_SHIFT;
    int nodes = min(NPB, N - n0);
    int ebase = bucketBase[b];
    int ecnt = bucketBase[b + 1] - ebase;

    cnt[t] = 0;
    __syncthreads();
    for (int i = t; i < ecnt; i += 256) {
        int d = dstA[ebase + i] - n0;
        atomicAdd(&cnt[d], 1);
    }
    __syncthreads();
    int v = cnt[t];
    sh[t] = v;
    __syncthreads();
    for (int off = 1; off < NPB; off <<= 1) {
        int u = (t >= off) ? sh[t - off] : 0;
        __syncthreads();
        sh[t] += u;
        __syncthreads();
    }
    int loff = sh[t] - v;  // exclusive
    if (t < nodes) offsets[n0 + t] = ebase + loff;
    cur[t] = ebase + loff;
    if (b == 0 && t == 0) offsets[N] = E;
    __syncthreads();
    for (int i = t; i < ecnt; i += 256) {
        int d = dstA[ebase + i] - n0;
        int p = atomicAdd(&cur[d], 1);
        rec[p] = rec8[ebase + i];
    }
}

// ---------------- Ut_l[j][a] = sum_k W_l[a][k] * w_ih[j][k] ----------------

__global__ void make_ut_k(const void* __restrict__ weight, const void* __restrict__ wih,
                          unsigned short* __restrict__ Ut, const int* __restrict__ flags) {
    int idx = blockIdx.x * 256 + threadIdx.x;  // l*49152 + j*128 + a
    if (idx >= 3 * 384 * 128) return;
    int isb = flags[0];
    int a = idx & 127;
    int j = (idx >> 7) % 384;
    int l = idx / (384 * 128);
    const unsigned short* Wb = (const unsigned short*)weight;
    const float* Wf = (const float*)weight;
    const unsigned short* Ib = (const unsigned short*)wih;
    const float* If = (const float*)wih;
    int wbase = l * 16384 + a * 128;
    int ibase = j * 128;
    float s = 0.f;
    if (isb) {
        for (int k = 0; k < 128; k++) s += bfu_to_f(Wb[wbase + k]) * bfu_to_f(Ib[ibase + k]);
    } else {
        for (int k = 0; k < 128; k++) s += Wf[wbase + k] * If[ibase + k];
    }
    Ut[idx] = f_to_bfu(s);
}

// ---------------- pack weights into MFMA B-fragment order ----------------
__global__ void pack_b_k(const unsigned short* __restrict__ Ut,
                         const void* __restrict__ whh,
                         unsigned short* __restrict__ Bp,
                         const int* __restrict__ flags) {
    int idx = blockIdx.x * 256 + threadIdx.x;  // 3*48*4*64 total
    if (idx >= 3 * 48 * 4 * 64) return;
    int l = idx / 12288;
    int rem = idx % 12288;
    int ct = rem >> 8;
    int kc = (rem >> 6) & 3;
    int lane = rem & 63;
    int col = (ct % 24) * 16 + (lane & 15);
    int k = kc * 32 + (lane >> 4) * 8;
    unsigned short tmp[8];
    const unsigned short* src;
    if (ct < 24) {
        src = Ut + (size_t)l * 49152 + col * 128 + k;
    } else if (flags[0]) {
        src = (const unsigned short*)whh + (size_t)col * 128 + k;
    } else {
        const float* wf = (const float*)whh + (size_t)col * 128 + k;
        for (int i = 0; i < 8; i++) tmp[i] = f_to_bfu(wf[i]);
        src = tmp;
    }
    unsigned short* dst = Bp + (size_t)l * 98304 + ((size_t)(ct * 4 + kc) * 64 + lane) * 8;
    for (int i = 0; i < 8; i++) dst[i] = src[i];
}

// ---------------- aggregation: y[n,:] = sum_{e: dst=n} w_e * xb[src_e,:] ----------------

__global__ __launch_bounds__(256) void agg_k(const unsigned short* __restrict__ xb,
                                             const int* __restrict__ offs,
                                             const uint2* __restrict__ rec,
                                             unsigned short* __restrict__ y, int N) {
    int node = (int)((blockIdx.x * 256 + threadIdx.x) >> 4);
    int l16 = threadIdx.x & 15;
    if (node >= N) return;
    int b = offs[node];
    int e2 = offs[node + 1];
    const uint4* xp4 = (const uint4*)xb;  // row = 16 uint4
    float a0[8], a1[8];
#pragma unroll
    for (int i = 0; i < 8; i++) { a0[i] = 0.f; a1[i] = 0.f; }

    auto fma_row = [&](float* acc, uint4 v, float w) {
        acc[0] += w * __builtin_bit_cast(float, v.x << 16);
        acc[1] += w * __builtin_bit_cast(float, v.x & 0xffff0000u);
        acc[2] += w * __builtin_bit_cast(float, v.y << 16);
        acc[3] += w * __builtin_bit_cast(float, v.y & 0xffff0000u);
        acc[4] += w * __builtin_bit_cast(float, v.z << 16);
        acc[5] += w * __builtin_bit_cast(float, v.z & 0xffff0000u);
        acc[6] += w * __builtin_bit_cast(float, v.w << 16);
        acc[7] += w * __builtin_bit_cast(float, v.w & 0xffff0000u);
    };

    int e = b;
    for (; e + 4 <= e2; e += 4) {
        uint2 r0 = rec[e], r1 = rec[e + 1], r2 = rec[e + 2], r3 = rec[e + 3];
        uint4 v0 = xp4[(size_t)r0.x * 16 + l16];
        uint4 v1 = xp4[(size_t)r1.x * 16 + l16];
        uint4 v2 = xp4[(size_t)r2.x * 16 + l16];
        uint4 v3 = xp4[(size_t)r3.x * 16 + l16];
        fma_row(a0, v0, __builtin_bit_cast(float, r0.y));
        fma_row(a1, v1, __builtin_bit_cast(float, r1.y));
        fma_row(a0, v2, __builtin_bit_cast(float, r2.y));
        fma_row(a1, v3, __builtin_bit_cast(float, r3.y));
    }
    for (; e < e2; e++) {
        uint2 r = rec[e];
        uint4 v = xp4[(size_t)r.x * 16 + l16];
        fma_row(a0, v, __builtin_bit_cast(float, r.y));
    }

    uint4 o;
    o.x = (unsigned int)f_to_bfu(a0[0] + a1[0]) | ((unsigned int)f_to_bfu(a0[1] + a1[1]) << 16);
    o.y = (unsigned int)f_to_bfu(a0[2] + a1[2]) | ((unsigned int)f_to_bfu(a0[3] + a1[3]) << 16);
    o.z = (unsigned int)f_to_bfu(a0[4] + a1[4]) | ((unsigned int)f_to_bfu(a0[5] + a1[5]) << 16);
    o.w = (unsigned int)f_to_bfu(a0[6] + a1[6]) | ((unsigned int)f_to_bfu(a0[7] + a1[7]) << 16);
    ((uint4*)y)[(size_t)node * 16 + l16] = o;
}

// ---------------- fused GRU: gi = y@Ut^T, gh = xin@whh^T, gates, write xout ----------------

__global__ __launch_bounds__(256) void gru_k(const unsigned short* __restrict__ y,
                                             const unsigned short* __restrict__ xin,
                                             unsigned short* __restrict__ xout,
                                             const unsigned short* __restrict__ Bp,
                                             const float* __restrict__ bih,
                                             const float* __restrict__ bhh, int N) {
    int tid = threadIdx.x;
    int wave = tid >> 6;
    int lane = tid & 63;
    int quad = lane >> 4;
    int m16 = lane & 15;
    int row0 = blockIdx.x * 32;

    floatx4 acc[2][2][6];  // [mt][t][g*2+p], p=0 -> gi (Ut), p=1 -> gh (whh)
#pragma unroll
    for (int mt = 0; mt < 2; mt++)
#pragma unroll
        for (int t = 0; t < 2; t++)
#pragma unroll
            for (int m = 0; m < 6; m++) acc[mt][t][m] = (floatx4){0.f, 0.f, 0.f, 0.f};

    int rA0 = row0 + m16;
    int rA1 = row0 + 16 + m16;
    if (rA0 >= N) rA0 = N - 1;
    if (rA1 >= N) rA1 = N - 1;

#pragma unroll
    for (int kc = 0; kc < 4; kc++) {
        int ko = kc * 32 + quad * 8;
        bf16x8 aY0 = *(const bf16x8*)(y + (size_t)rA0 * 128 + ko);
        bf16x8 aY1 = *(const bf16x8*)(y + (size_t)rA1 * 128 + ko);
        bf16x8 aX0 = *(const bf16x8*)(xin + (size_t)rA0 * 128 + ko);
        bf16x8 aX1 = *(const bf16x8*)(xin + (size_t)rA1 * 128 + ko);
#pragma unroll
        for (int t = 0; t < 2; t++) {
            int ctt = wave * 2 + t;
#pragma unroll
            for (int g = 0; g < 3; g++) {
                int ctU = g * 8 + ctt;
                bf16x8 bU = *(const bf16x8*)(Bp + ((size_t)(ctU * 4 + kc) * 64 + lane) * 8);
                acc[0][t][g * 2 + 0] =
                    __builtin_amdgcn_mfma_f32_16x16x32_bf16(aY0, bU, acc[0][t][g * 2 + 0], 0, 0, 0);
                acc[1][t][g * 2 + 0] =
                    __builtin_amdgcn_mfma_f32_16x16x32_bf16(aY1, bU, acc[1][t][g * 2 + 0], 0, 0, 0);
                int ctW = 24 + g * 8 + ctt;
                bf16x8 bW = *(const bf16x8*)(Bp + ((size_t)(ctW * 4 + kc) * 64 + lane) * 8);
                acc[0][t][g * 2 + 1] =
                    __builtin_amdgcn_mfma_f32_16x16x32_bf16(aX0, bW, acc[0][t][g * 2 + 1], 0, 0, 0);
                acc[1][t][g * 2 + 1] =
                    __builtin_amdgcn_mfma_f32_16x16x32_bf16(aX1, bW, acc[1][t][g * 2 + 1], 0, 0, 0);
            }
        }
    }

#pragma unroll
    for (int t = 0; t < 2; t++) {
        int ch = wave * 32 + t * 16 + m16;
        float bi_r = bih[ch], bh_r = bhh[ch];
        float bi_z = bih[128 + ch], bh_z = bhh[128 + ch];
        float bi_n = bih[256 + ch], bh_n = bhh[256 + ch];
#pragma unroll
        for (int mt = 0; mt < 2; mt++) {
#pragma unroll
            for (int ri = 0; ri < 4; ri++) {
                int row = row0 + mt * 16 + quad * 4 + ri;
                if (row >= N) continue;
                float gir = acc[mt][t][0][ri] + bi_r, ghr = acc[mt][t][1][ri] + bh_r;
                float giz = acc[mt][t][2][ri] + bi_z, ghz = acc[mt][t][3][ri] + bh_z;
                float gin = acc[mt][t][4][ri] + bi_n, ghn = acc[mt][t][5][ri] + bh_n;
                float r = 1.f / (1.f + __expf(-(gir + ghr)));
                float zg = 1.f / (1.f + __expf(-(giz + ghz)));
                float n = tanhf(gin + r * ghn);
                float h = bfu_to_f(xin[(size_t)row * 128 + ch]);
                float o = (1.f - zg) * n + zg * h;
                xout[(size_t)row * 128 + ch] = f_to_bfu(o);
            }
        }
    }
}

// ---------------- launch ----------------

extern "C" void kernel_launch(void* const* d_in, const int* in_sizes, int n_in,
                              void* d_out, int out_size, void* d_ws, size_t ws_size,
                              hipStream_t stream) {
    const int N = in_sizes[0] / 128;
    const int E = in_sizes[1];
    const int NB = (N + NPB - 1) >> NPB_SHIFT;

    const void* z = d_in[0];
    const void* ew = d_in[1];
    const void* weight = d_in[2];
    const void* wih = d_in[3];
    const void* whh = d_in[4];
    const void* bih = d_in[5];
    const void* bhh = d_in[6];
    const unsigned int* eiu = (const unsigned int*)d_in[7];

    // y (bf16 N*128 = 25.6MB) aliases d_out — dead before final out_k write.
    unsigned short* y = (unsigned short*)d_out;

    size_t off = 0;
    char* base = (char*)d_ws;
    auto carve = [&](size_t bytes) -> void* {
        void* p = base + off;
        off = (off + bytes + 255) & ~(size_t)255;
        return p;
    };
    unsigned short* xb = (unsigned short*)carve((size_t)N * 128 * 2);
    unsigned short* xb2 = (unsigned short*)carve((size_t)N * 128 * 2);
    uint2* rec8 = (uint2*)carve((size_t)E * 8);   // binned (src,w)
    int* dstA = (int*)carve((size_t)E * 4);       // binned dst
    uint2* rec = (uint2*)carve((size_t)E * 8);    // final CSR records
    int* offsets = (int*)carve((size_t)(N + 1) * 4);
    int* bucketCnt = (int*)carve(MAXNB * 4);
    int* bucketBase = (int*)carve((MAXNB + 1) * 4);
    int* bucketCursor = (int*)carve(MAXNB * 4);
    unsigned short* Ut = (unsigned short*)carve((size_t)3 * 384 * 128 * 2);
    unsigned short* Bp = (unsigned short*)carve((size_t)3 * 48 * 4 * 64 * 8 * 2);
    float* bih_f = (float*)carve(384 * 4);
    float* bhh_f = (float*)carve(384 * 4);
    int* flags = (int*)carve(256);

    detect_k<<<1, 64, 0, stream>>>((const unsigned short*)bih, eiu, flags);

    cvt_bf16_k<<<(N * 128 + 255) / 256, 256, 0, stream>>>(z, xb, N * 128, flags);
    cvt_bias_k<<<3, 256, 0, stream>>>(bih, bhh, bih_f, bhh_f, flags);

    // hierarchical CSR build
    hipMemsetAsync(bucketCnt, 0, MAXNB * 4, stream);
    int gbin = (E + TILE - 1) / TILE;
    count_k<<<gbin, 256, 0, stream>>>(eiu, bucketCnt, E, flags);
    scanB_k<<<1, MAXNB, 0, stream>>>(bucketCnt, bucketBase, bucketCursor, NB, E);
    bin_k<<<gbin, 256, 0, stream>>>(eiu, ew, bucketCursor, rec8, dstA, E, flags);
    csr_k<<<NB, NPB, 0, stream>>>(rec8, dstA, bucketBase, offsets, rec, N, E);

    make_ut_k<<<(3 * 384 * 128 + 255) / 256, 256, 0, stream>>>(weight, wih, Ut, flags);
    pack_b_k<<<(3 * 48 * 4 * 64 + 255) / 256, 256, 0, stream>>>(Ut, whh, Bp, flags);

    const unsigned short* cur = xb;
    unsigned short* nxt = xb2;
    for (int l = 0; l < 3; l++) {
        agg_k<<<(N + 15) / 16, 256, 0, stream>>>(cur, offsets, rec, y, N);
        gru_k<<<(N + 31) / 32, 256, 0, stream>>>(y, cur, nxt, Bp + (size_t)l * 98304,
                                                 bih_f, bhh_f, N);
        const unsigned short* tmp = cur;
        cur = nxt;
        nxt = (unsigned short*)tmp;
    }

    out_k<<<(N * 128 + 255) / 256, 256, 0, stream>>>(cur, d_out, N * 128, flags);
}

// Round 7
// 732.142 us; speedup vs baseline: 1.7610x; 1.0167x over previous
//
#include <hip/hip_runtime.h>

typedef __bf16 bf16x8 __attribute__((ext_vector_type(8)));
typedef float floatx4 __attribute__((ext_vector_type(4)));

#define NPB 256        // nodes per bucket (power of 2)
#define NPB_SHIFT 8
#define MAXNB 1024     // max buckets supported (N <= 262144)
#define TILE 16384     // edges per binning block

static __device__ __forceinline__ float bfu_to_f(unsigned short u) {
    unsigned int x = ((unsigned int)u) << 16;
    return __builtin_bit_cast(float, x);
}
static __device__ __forceinline__ unsigned short f_to_bfu(float f) {
    unsigned int u = __builtin_bit_cast(unsigned int, f);
    unsigned int r = (u + 0x7fffu + ((u >> 16) & 1u)) >> 16;
    return (unsigned short)r;
}

// ---------------- dtype detection ----------------
__global__ void detect_k(const unsigned short* __restrict__ bih_u,
                         const unsigned int* __restrict__ ei_u,
                         int* __restrict__ flags) {
    if (threadIdx.x == 0 && blockIdx.x == 0) {
        int votes = 0;
        for (int i = 0; i < 64; i++) {
            unsigned short u = bih_u[2 * i];
            unsigned int ex = (u >> 7) & 0xFF;
            if (ex >= 64 && ex < 124) votes++;
        }
        flags[0] = (votes >= 48) ? 1 : 0;
        int zeros = 0;
        for (int i = 0; i < 64; i++) {
            if (ei_u[2 * i + 1] == 0u) zeros++;
        }
        flags[1] = (zeros == 64) ? 1 : 0;
    }
}

// ---------------- canonicalization ----------------

__global__ void cvt_bf16_k(const void* __restrict__ in, unsigned short* __restrict__ out,
                           int n, const int* __restrict__ flags) {
    int i = blockIdx.x * 256 + threadIdx.x;
    if (i >= n) return;
    if (flags[0]) out[i] = ((const unsigned short*)in)[i];
    else out[i] = f_to_bfu(((const float*)in)[i]);
}

__global__ void cvt_bias_k(const void* __restrict__ bih, const void* __restrict__ bhh,
                           float* __restrict__ bih_f, float* __restrict__ bhh_f,
                           const int* __restrict__ flags) {
    int i = blockIdx.x * 256 + threadIdx.x;
    if (i >= 768) return;
    const void* src = (i < 384) ? bih : bhh;
    int j = (i < 384) ? i : i - 384;
    float v = flags[0] ? bfu_to_f(((const unsigned short*)src)[j]) : ((const float*)src)[j];
    if (i < 384) bih_f[j] = v;
    else bhh_f[j] = v;
}

__global__ void out_k(const unsigned short* __restrict__ xb, void* __restrict__ out,
                      int n, const int* __restrict__ flags) {
    int i = blockIdx.x * 256 + threadIdx.x;
    if (i >= n) return;
    if (flags[0]) ((unsigned short*)out)[i] = xb[i];
    else ((float*)out)[i] = bfu_to_f(xb[i]);
}

// ---------------- hierarchical CSR build ----------------

static __device__ __forceinline__ int load_idx(const unsigned int* eiu, size_t pos, int is64) {
    return (int)eiu[is64 ? 2 * pos : pos];
}

__global__ __launch_bounds__(256) void count_k(const unsigned int* __restrict__ eiu,
                                               int* __restrict__ bucketCnt, int E,
                                               const int* __restrict__ flags) {
    __shared__ int cnt[MAXNB];
    int t = threadIdx.x;
    for (int b = t; b < MAXNB; b += 256) cnt[b] = 0;
    __syncthreads();
    int is64 = flags[1];
    int e0 = blockIdx.x * TILE;
    int e1 = min(e0 + TILE, E);
    for (int e = e0 + t; e < e1; e += 256) {
        int d = load_idx(eiu, (size_t)E + e, is64);
        atomicAdd(&cnt[d >> NPB_SHIFT], 1);
    }
    __syncthreads();
    for (int b = t; b < MAXNB; b += 256) {
        int c = cnt[b];
        if (c) atomicAdd(&bucketCnt[b], c);
    }
}

__global__ void scanB_k(const int* __restrict__ bucketCnt, int* __restrict__ bucketBase,
                        int* __restrict__ bucketCursor, int NB, int E) {
    __shared__ int sh[MAXNB];
    int t = threadIdx.x;  // 1024 threads
    int v = (t < NB) ? bucketCnt[t] : 0;
    sh[t] = v;
    __syncthreads();
    for (int off = 1; off < MAXNB; off <<= 1) {
        int u = (t >= off) ? sh[t - off] : 0;
        __syncthreads();
        sh[t] += u;
        __syncthreads();
    }
    if (t < NB) {
        int b = sh[t] - v;
        bucketBase[t] = b;
        bucketCursor[t] = b;
    }
    if (t == 0) bucketBase[NB] = E;
}

__global__ __launch_bounds__(256) void bin_k(const unsigned int* __restrict__ eiu,
                                             const void* __restrict__ ew,
                                             int* __restrict__ bucketCursor,
                                             uint2* __restrict__ rec8,
                                             int* __restrict__ dstA, int E,
                                             const int* __restrict__ flags) {
    __shared__ int cnt[MAXNB];
    __shared__ int basel[MAXNB];
    int t = threadIdx.x;
    for (int b = t; b < MAXNB; b += 256) cnt[b] = 0;
    __syncthreads();
    int is64 = flags[1];
    int isb = flags[0];
    int e0 = blockIdx.x * TILE;
    int e1 = min(e0 + TILE, E);
    for (int e = e0 + t; e < e1; e += 256) {
        int d = load_idx(eiu, (size_t)E + e, is64);
        atomicAdd(&cnt[d >> NPB_SHIFT], 1);
    }
    __syncthreads();
    for (int b = t; b < MAXNB; b += 256) {
        int c = cnt[b];
        basel[b] = c ? atomicAdd(&bucketCursor[b], c) : 0;
        cnt[b] = 0;
    }
    __syncthreads();
    for (int e = e0 + t; e < e1; e += 256) {
        int s = load_idx(eiu, (size_t)e, is64);
        int d = load_idx(eiu, (size_t)E + e, is64);
        float w = isb ? bfu_to_f(((const unsigned short*)ew)[e]) : ((const float*)ew)[e];
        int b = d >> NPB_SHIFT;
        int p = basel[b] + atomicAdd(&cnt[b], 1);
        dstA[p] = d;
        rec8[p] = make_uint2((unsigned int)s, __builtin_bit_cast(unsigned int, w));
    }
}

__global__ __launch_bounds__(256) void csr_k(const uint2* __restrict__ rec8,
                                             const int* __restrict__ dstA,
                                             const int* __restrict__ bucketBase,
                                             int* __restrict__ offsets,
                                             uint2* __restrict__ rec, int N, int E) {
    __shared__ int cnt[NPB];
    __shared__ int sh[NPB];
    __shared__ int cur[NPB];
    int t = threadIdx.x;
    int b = blockIdx.x;
    int n0 = b << NPB_SHIFT;
    int nodes = min(NPB, N - n0);
    int ebase = bucketBase[b];
    int ecnt = bucketBase[b + 1] - ebase;

    cnt[t] = 0;
    __syncthreads();
    for (int i = t; i < ecnt; i += 256) {
        int d = dstA[ebase + i] - n0;
        atomicAdd(&cnt[d], 1);
    }
    __syncthreads();
    int v = cnt[t];
    sh[t] = v;
    __syncthreads();
    for (int off = 1; off < NPB; off <<= 1) {
        int u = (t >= off) ? sh[t - off] : 0;
        __syncthreads();
        sh[t] += u;
        __syncthreads();
    }
    int loff = sh[t] - v;  // exclusive
    if (t < nodes) offsets[n0 + t] = ebase + loff;
    cur[t] = ebase + loff;
    if (b == 0 && t == 0) offsets[N] = E;
    __syncthreads();
    for (int i = t; i < ecnt; i += 256) {
        int d = dstA[ebase + i] - n0;
        int p = atomicAdd(&cur[d], 1);
        rec[p] = rec8[ebase + i];
    }
}

// ---------------- Ut_l[j][a] = sum_k W_l[a][k] * w_ih[j][k] ----------------

__global__ void make_ut_k(const void* __restrict__ weight, const void* __restrict__ wih,
                          unsigned short* __restrict__ Ut, const int* __restrict__ flags) {
    int idx = blockIdx.x * 256 + threadIdx.x;  // l*49152 + j*128 + a
    if (idx >= 3 * 384 * 128) return;
    int isb = flags[0];
    int a = idx & 127;
    int j = (idx >> 7) % 384;
    int l = idx / (384 * 128);
    const unsigned short* Wb = (const unsigned short*)weight;
    const float* Wf = (const float*)weight;
    const unsigned short* Ib = (const unsigned short*)wih;
    const float* If = (const float*)wih;
    int wbase = l * 16384 + a * 128;
    int ibase = j * 128;
    float s = 0.f;
    if (isb) {
        for (int k = 0; k < 128; k++) s += bfu_to_f(Wb[wbase + k]) * bfu_to_f(Ib[ibase + k]);
    } else {
        for (int k = 0; k < 128; k++) s += Wf[wbase + k] * If[ibase + k];
    }
    Ut[idx] = f_to_bfu(s);
}

// ---------------- pack weights into MFMA B-fragment order ----------------
// Bp[l][ct][kc][lane][8]: ct 0..23 = Ut col-tiles (col = (ct%24)*16 + lane&15),
// ct 24..47 = whh col-tiles; kc = K-chunk of 32; lane fragment = 8 bf16 at
// k = kc*32 + (lane>>4)*8.
__global__ void pack_b_k(const unsigned short* __restrict__ Ut,
                         const void* __restrict__ whh,
                         unsigned short* __restrict__ Bp,
                         const int* __restrict__ flags) {
    int idx = blockIdx.x * 256 + threadIdx.x;  // 3*48*4*64 total
    if (idx >= 3 * 48 * 4 * 64) return;
    int l = idx / 12288;
    int rem = idx % 12288;
    int ct = rem >> 8;
    int kc = (rem >> 6) & 3;
    int lane = rem & 63;
    int col = (ct % 24) * 16 + (lane & 15);
    int k = kc * 32 + (lane >> 4) * 8;
    unsigned short tmp[8];
    const unsigned short* src;
    if (ct < 24) {
        src = Ut + (size_t)l * 49152 + col * 128 + k;
    } else if (flags[0]) {
        src = (const unsigned short*)whh + (size_t)col * 128 + k;
    } else {
        const float* wf = (const float*)whh + (size_t)col * 128 + k;
        for (int i = 0; i < 8; i++) tmp[i] = f_to_bfu(wf[i]);
        src = tmp;
    }
    unsigned short* dst = Bp + (size_t)l * 98304 + ((size_t)(ct * 4 + kc) * 64 + lane) * 8;
    for (int i = 0; i < 8; i++) dst[i] = src[i];
}

// ---------------- aggregation: y[n,:] = sum_{e: dst=n} w_e * xb[src_e,:] ----------------

__global__ __launch_bounds__(256) void agg_k(const unsigned short* __restrict__ xb,
                                             const int* __restrict__ offs,
                                             const uint2* __restrict__ rec,
                                             unsigned short* __restrict__ y, int N) {
    int node = (int)((blockIdx.x * 256 + threadIdx.x) >> 4);
    int l16 = threadIdx.x & 15;
    if (node >= N) return;
    int b = offs[node];
    int e2 = offs[node + 1];
    const uint4* xp4 = (const uint4*)xb;  // row = 16 uint4
    float a0[8], a1[8];
#pragma unroll
    for (int i = 0; i < 8; i++) { a0[i] = 0.f; a1[i] = 0.f; }

    auto fma_row = [&](float* acc, uint4 v, float w) {
        acc[0] += w * __builtin_bit_cast(float, v.x << 16);
        acc[1] += w * __builtin_bit_cast(float, v.x & 0xffff0000u);
        acc[2] += w * __builtin_bit_cast(float, v.y << 16);
        acc[3] += w * __builtin_bit_cast(float, v.y & 0xffff0000u);
        acc[4] += w * __builtin_bit_cast(float, v.z << 16);
        acc[5] += w * __builtin_bit_cast(float, v.z & 0xffff0000u);
        acc[6] += w * __builtin_bit_cast(float, v.w << 16);
        acc[7] += w * __builtin_bit_cast(float, v.w & 0xffff0000u);
    };

    int e = b;
    for (; e + 4 <= e2; e += 4) {
        uint2 r0 = rec[e], r1 = rec[e + 1], r2 = rec[e + 2], r3 = rec[e + 3];
        uint4 v0 = xp4[(size_t)r0.x * 16 + l16];
        uint4 v1 = xp4[(size_t)r1.x * 16 + l16];
        uint4 v2 = xp4[(size_t)r2.x * 16 + l16];
        uint4 v3 = xp4[(size_t)r3.x * 16 + l16];
        fma_row(a0, v0, __builtin_bit_cast(float, r0.y));
        fma_row(a1, v1, __builtin_bit_cast(float, r1.y));
        fma_row(a0, v2, __builtin_bit_cast(float, r2.y));
        fma_row(a1, v3, __builtin_bit_cast(float, r3.y));
    }
    for (; e < e2; e++) {
        uint2 r = rec[e];
        uint4 v = xp4[(size_t)r.x * 16 + l16];
        fma_row(a0, v, __builtin_bit_cast(float, r.y));
    }

    uint4 o;
    o.x = (unsigned int)f_to_bfu(a0[0] + a1[0]) | ((unsigned int)f_to_bfu(a0[1] + a1[1]) << 16);
    o.y = (unsigned int)f_to_bfu(a0[2] + a1[2]) | ((unsigned int)f_to_bfu(a0[3] + a1[3]) << 16);
    o.z = (unsigned int)f_to_bfu(a0[4] + a1[4]) | ((unsigned int)f_to_bfu(a0[5] + a1[5]) << 16);
    o.w = (unsigned int)f_to_bfu(a0[6] + a1[6]) | ((unsigned int)f_to_bfu(a0[7] + a1[7]) << 16);
    ((uint4*)y)[(size_t)node * 16 + l16] = o;
}

// ---------------- fused GRU: gi = y@Ut^T, gh = xin@whh^T, gates, write xout ----------------
// 512 threads / 8 waves, M = 32 rows/block. Wave w owns 16 output channels
// [w*16, w*16+16): acc = 48 VGPRs/wave (vs 96 in the 4-wave version) so the
// compiler can keep more B-fragment loads in flight; 2 blocks/CU x 8 waves
// give real latency overlap.

__global__ __launch_bounds__(512) void gru_k(const unsigned short* __restrict__ y,
                                             const unsigned short* __restrict__ xin,
                                             unsigned short* __restrict__ xout,
                                             const unsigned short* __restrict__ Bp,
                                             const float* __restrict__ bih,
                                             const float* __restrict__ bhh, int N) {
    int tid = threadIdx.x;
    int wave = tid >> 6;   // 0..7 = col-tile
    int lane = tid & 63;
    int quad = lane >> 4;
    int m16 = lane & 15;
    int row0 = blockIdx.x * 32;

    floatx4 acc[2][6];  // [mt][g*2+p], p=0 -> gi (Ut), p=1 -> gh (whh)
#pragma unroll
    for (int mt = 0; mt < 2; mt++)
#pragma unroll
        for (int m = 0; m < 6; m++) acc[mt][m] = (floatx4){0.f, 0.f, 0.f, 0.f};

    int rA0 = row0 + m16;
    int rA1 = row0 + 16 + m16;
    if (rA0 >= N) rA0 = N - 1;
    if (rA1 >= N) rA1 = N - 1;

#pragma unroll
    for (int kc = 0; kc < 4; kc++) {
        int ko = kc * 32 + quad * 8;
        bf16x8 aY0 = *(const bf16x8*)(y + (size_t)rA0 * 128 + ko);
        bf16x8 aY1 = *(const bf16x8*)(y + (size_t)rA1 * 128 + ko);
        bf16x8 aX0 = *(const bf16x8*)(xin + (size_t)rA0 * 128 + ko);
        bf16x8 aX1 = *(const bf16x8*)(xin + (size_t)rA1 * 128 + ko);
#pragma unroll
        for (int g = 0; g < 3; g++) {
            int ctU = g * 8 + wave;
            bf16x8 bU = *(const bf16x8*)(Bp + ((size_t)(ctU * 4 + kc) * 64 + lane) * 8);
            acc[0][g * 2 + 0] =
                __builtin_amdgcn_mfma_f32_16x16x32_bf16(aY0, bU, acc[0][g * 2 + 0], 0, 0, 0);
            acc[1][g * 2 + 0] =
                __builtin_amdgcn_mfma_f32_16x16x32_bf16(aY1, bU, acc[1][g * 2 + 0], 0, 0, 0);
            int ctW = 24 + g * 8 + wave;
            bf16x8 bW = *(const bf16x8*)(Bp + ((size_t)(ctW * 4 + kc) * 64 + lane) * 8);
            acc[0][g * 2 + 1] =
                __builtin_amdgcn_mfma_f32_16x16x32_bf16(aX0, bW, acc[0][g * 2 + 1], 0, 0, 0);
            acc[1][g * 2 + 1] =
                __builtin_amdgcn_mfma_f32_16x16x32_bf16(aX1, bW, acc[1][g * 2 + 1], 0, 0, 0);
        }
    }

    int ch = wave * 16 + m16;  // 0..127
    float bi_r = bih[ch], bh_r = bhh[ch];
    float bi_z = bih[128 + ch], bh_z = bhh[128 + ch];
    float bi_n = bih[256 + ch], bh_n = bhh[256 + ch];
#pragma unroll
    for (int mt = 0; mt < 2; mt++) {
#pragma unroll
        for (int ri = 0; ri < 4; ri++) {
            int row = row0 + mt * 16 + quad * 4 + ri;
            if (row >= N) continue;
            float gir = acc[mt][0][ri] + bi_r, ghr = acc[mt][1][ri] + bh_r;
            float giz = acc[mt][2][ri] + bi_z, ghz = acc[mt][3][ri] + bh_z;
            float gin = acc[mt][4][ri] + bi_n, ghn = acc[mt][5][ri] + bh_n;
            float r = 1.f / (1.f + __expf(-(gir + ghr)));
            float zg = 1.f / (1.f + __expf(-(giz + ghz)));
            float n = tanhf(gin + r * ghn);
            float h = bfu_to_f(xin[(size_t)row * 128 + ch]);
            float o = (1.f - zg) * n + zg * h;
            xout[(size_t)row * 128 + ch] = f_to_bfu(o);
        }
    }
}

// ---------------- launch ----------------

extern "C" void kernel_launch(void* const* d_in, const int* in_sizes, int n_in,
                              void* d_out, int out_size, void* d_ws, size_t ws_size,
                              hipStream_t stream) {
    const int N = in_sizes[0] / 128;
    const int E = in_sizes[1];
    const int NB = (N + NPB - 1) >> NPB_SHIFT;

    const void* z = d_in[0];
    const void* ew = d_in[1];
    const void* weight = d_in[2];
    const void* wih = d_in[3];
    const void* whh = d_in[4];
    const void* bih = d_in[5];
    const void* bhh = d_in[6];
    const unsigned int* eiu = (const unsigned int*)d_in[7];

    // y (bf16 N*128 = 25.6MB) aliases d_out — dead before final out_k write.
    unsigned short* y = (unsigned short*)d_out;

    size_t off = 0;
    char* base = (char*)d_ws;
    auto carve = [&](size_t bytes) -> void* {
        void* p = base + off;
        off = (off + bytes + 255) & ~(size_t)255;
        return p;
    };
    unsigned short* xb = (unsigned short*)carve((size_t)N * 128 * 2);
    unsigned short* xb2 = (unsigned short*)carve((size_t)N * 128 * 2);
    uint2* rec8 = (uint2*)carve((size_t)E * 8);   // binned (src,w)
    int* dstA = (int*)carve((size_t)E * 4);       // binned dst
    uint2* rec = (uint2*)carve((size_t)E * 8);    // final CSR records
    int* offsets = (int*)carve((size_t)(N + 1) * 4);
    int* bucketCnt = (int*)carve(MAXNB * 4);
    int* bucketBase = (int*)carve((MAXNB + 1) * 4);
    int* bucketCursor = (int*)carve(MAXNB * 4);
    unsigned short* Ut = (unsigned short*)carve((size_t)3 * 384 * 128 * 2);
    unsigned short* Bp = (unsigned short*)carve((size_t)3 * 48 * 4 * 64 * 8 * 2);
    float* bih_f = (float*)carve(384 * 4);
    float* bhh_f = (float*)carve(384 * 4);
    int* flags = (int*)carve(256);

    detect_k<<<1, 64, 0, stream>>>((const unsigned short*)bih, eiu, flags);

    cvt_bf16_k<<<(N * 128 + 255) / 256, 256, 0, stream>>>(z, xb, N * 128, flags);
    cvt_bias_k<<<3, 256, 0, stream>>>(bih, bhh, bih_f, bhh_f, flags);

    // hierarchical CSR build
    hipMemsetAsync(bucketCnt, 0, MAXNB * 4, stream);
    int gbin = (E + TILE - 1) / TILE;
    count_k<<<gbin, 256, 0, stream>>>(eiu, bucketCnt, E, flags);
    scanB_k<<<1, MAXNB, 0, stream>>>(bucketCnt, bucketBase, bucketCursor, NB, E);
    bin_k<<<gbin, 256, 0, stream>>>(eiu, ew, bucketCursor, rec8, dstA, E, flags);
    csr_k<<<NB, NPB, 0, stream>>>(rec8, dstA, bucketBase, offsets, rec, N, E);

    make_ut_k<<<(3 * 384 * 128 + 255) / 256, 256, 0, stream>>>(weight, wih, Ut, flags);
    pack_b_k<<<(3 * 48 * 4 * 64 + 255) / 256, 256, 0, stream>>>(Ut, whh, Bp, flags);

    const unsigned short* cur = xb;
    unsigned short* nxt = xb2;
    for (int l = 0; l < 3; l++) {
        agg_k<<<(N + 15) / 16, 256, 0, stream>>>(cur, offsets, rec, y, N);
        gru_k<<<(N + 31) / 32, 512, 0, stream>>>(y, cur, nxt, Bp + (size_t)l * 98304,
                                                 bih_f, bhh_f, N);
        const unsigned short* tmp = cur;
        cur = nxt;
        nxt = (unsigned short*)tmp;
    }

    out_k<<<(N * 128 + 255) / 256, 256, 0, stream>>>(cur, d_out, N * 128, flags);
}